// Round 1
// baseline (415.151 us; speedup 1.0000x reference)
//
#include <hip/hip_runtime.h>
#include <stdint.h>

// W8A8B32O32 Linear: Y[m,n] = round(out_scale * sum_k X[m,k]*W[n,k] + bias_scale * bias[n])
// Harness materializes integer inputs as int32 -> pre-pass packs to int8 in d_ws (exact),
// then DMA-staged mfma_i32_16x16x64_i8 GEMM.
//
// Round 6: port of the verified 256^2 8-phase schedule (plain-HIP HK template) to i8.
//  - 256x256 tile, BK=128 (128 B rows, identical byte geometry to the bf16 BK=64 template)
//  - 8 waves (512 thr), wave grid 2M x 4N -> 128x64 per wave (85 int-ops/LDS-byte; the old
//    64x64/wave needed ~100 B/cy of ds_read_b128 vs the 85 B/cy ceiling -> LDS-read bound)
//  - double-buffered 128 KiB LDS, XOR chunk swizzle (chunk j of row r at slot j^(r&7)) via
//    pre-swizzled global source addresses; zero bank conflicts (carried over, verified)
//  - 4 phases per K-tile: {ds_read subtile || stage 1 half-tile -> s_barrier ->
//    lgkmcnt(0) -> setprio(1) 16xMFMA setprio(0) -> s_barrier}
//  - counted s_waitcnt vmcnt(4) ONCE per K-tile (A-halves of tile t+2 stay in flight
//    across barriers); prologue stages tile0 + A(1), vmcnt(4)
//  - 2D XCD-chunked block swizzle: each XCD owns an 8x8 block of tiles (A 4 MB + B 8 MB
//    per round, K-lockstep working set ~400 KB -> L2-resident)
//
// Stage/read hazard ledger (phases P1..P4 of tile t, buffers buf[t&1]):
//   reads: P1: A[i0..3]+B[j0..1], P2: A[i4..7], P3: B[j2..3], P4: none
//   -> A regions retire P2, B regions retire P3 (region = wave-subset's full rows/cols)
//   stages: P1: Bh0(t+1) [B(t-1) retired t-1P3], P2: Bh1(t+1),
//           P3: Ah0(t+2) [A(t) retired tP2],     P4: Ah1(t+2)
//   every overwrite is >=1 closing barrier after its region's last read's lgkmcnt(0).
//   vmcnt(4) at tP4: FIFO = [.., A(t+1)x4 (t-1P3/P4), B(t+1)x4 (tP1/P2), A(t+2)x4] ->
//   waits tile t+1 fully landed, leaves A(t+2) in flight. Tail: vmcnt(0) for t>=KT-2.
//
// NOTE: per-replay dur_us includes ~200us fixed harness restore/poison; GEMM is the lever.

typedef int v4i __attribute__((ext_vector_type(4)));

#define BM 256
#define BN 256
#define BK 128
#define KK 4096
#define KT (KK / BK)   // 32

// ---------------- pack: 4x int32 -> 4x int8 in one dword (coalesced, ~roofline) ----------------
__global__ __launch_bounds__(256)
void pack_i32_to_i8(const v4i* __restrict__ src, int* __restrict__ dst, int n4) {
    int i = blockIdx.x * blockDim.x + threadIdx.x;   // one thread = 4 elements
    if (i >= n4) return;
    v4i a = src[i];
    dst[i] = (a[0] & 0xff) | ((a[1] & 0xff) << 8) | ((a[2] & 0xff) << 16) | (a[3] << 24);
}

// ---------------- GEMM ----------------
__device__ __forceinline__ void gld_lds16(const void* g, void* lds) {
    __builtin_amdgcn_global_load_lds(
        (const __attribute__((address_space(1))) unsigned int*)g,
        (__attribute__((address_space(3))) unsigned int*)lds,
        16, 0, 0);
}

#define MFMA_I8 __builtin_amdgcn_mfma_i32_16x16x64_i8
#define BARRIER() __builtin_amdgcn_s_barrier()
#define LGKM0() asm volatile("s_waitcnt lgkmcnt(0)" ::: "memory")
#define PRIO(x) __builtin_amdgcn_s_setprio(x)

__global__ __launch_bounds__(512, 2)
void w8a8_gemm_kernel(const int8_t* __restrict__ X,
                      const int8_t* __restrict__ W,
                      const int*    __restrict__ bias,
                      const float*  __restrict__ out_scale_p,
                      const float*  __restrict__ bias_scale_p,
                      int*          __restrict__ Y,
                      int M, int N)
{
    __shared__ __align__(16) int8_t sA[2 * BM * BK];  // 64 KB (double-buffered)
    __shared__ __align__(16) int8_t sB[2 * BN * BK];  // 64 KB

    const int tid = threadIdx.x;         // 0..511

    // ---- block -> tile mapping with 2D XCD chunking (8 XCDs, each owns 8x8 tiles) ----
    const int nbx = N / BN;              // 16 expected
    const int nby = M / BM;              // 32 expected
    int bx, by;
    {
        const int wg = blockIdx.x;
        if (nbx == 16 && nby == 32) {
            const int x = wg & 7;        // XCD (dispatch round-robins blockIdx % 8)
            const int k = wg >> 3;       // 0..63 within XCD
            bx = ((x & 1) << 3) | (k & 7);
            by = ((x >> 1) << 3) | (k >> 3);
        } else { bx = wg % nbx; by = wg / nbx; }
    }
    const int bn = bx * BN;
    const int bm = by * BM;

    const float out_scale  = *out_scale_p;
    const float bias_scale = *bias_scale_p;

    const int8_t* Abase = X + (size_t)bm * KK;
    const int8_t* Bbase = W + (size_t)bn * KK;

    // ---- staging thread map: half-tile = 128 rows x 8 chunks(16B) = 1024 chunks, 2 rounds ----
    // LDS slot c (linear, c = q*512 + tid) holds global chunk (c&7)^(row&7) of row c>>3
    // -> XOR swizzle via SOURCE address permutation, LDS dest stays linear (DMA-compatible).
    const int r0  = tid >> 3;                       // 0..63 (round 0 rows; round 1 = +64)
    const int j0  = tid & 7;
    const int sw  = (j0 ^ (r0 & 7)) << 4;           // pre-swizzled in-row byte offset
    const size_t gOff = (size_t)r0 * KK + sw;
    const int  lOff = tid << 4;

#define STAGE(gbase, lds, t, h) do {                                              \
        const int8_t* _g = (gbase) + (size_t)((h) * 128) * KK                     \
                                   + (size_t)(t) * BK + gOff;                     \
        int8_t* _l = (lds) + (((t) & 1) << 15) + ((h) << 14) + lOff;              \
        gld_lds16(_g,                  _l);                                       \
        gld_lds16(_g + (size_t)64 * KK, _l + 8192);                               \
    } while (0)

    // ---- fragment read map (verified 16x16x64 layout: lane = (tm, quad)) ----
    const int w    = tid >> 6;
    const int l    = tid & 63;
    const int wmw  = w >> 2;                        // 0..1  (M wave)
    const int wnw  = w & 3;                         // 0..3  (N wave)
    const int tm   = l & 15;
    const int quad = l >> 4;
    const int s3   = tm & 7;                        // row&7 (wave row bases are mult of 8)
    const int xo0  = ( quad      ^ s3) << 4;        // ks=0: chunk quad
    const int xo1  = ((quad + 4) ^ s3) << 4;        // ks=1: chunk 4+quad
    const int rowA = ((wmw << 7) + tm) << 7;        // (wm*128+tm)*128 bytes
    const int rowB = ((wnw << 6) + tm) << 7;        // (wn*64 +tm)*128 bytes

    v4i acc[8][4];
    const v4i vz = {0, 0, 0, 0};
#pragma unroll
    for (int i = 0; i < 8; ++i)
#pragma unroll
        for (int j = 0; j < 4; ++j)
            acc[i][j] = vz;

    // ---- prologue: tile 0 (A+B) + tile 1 (A only); B(1) comes in-loop at t=0 P1/P2 ----
    STAGE(Abase, sA, 0, 0); STAGE(Abase, sA, 0, 1);
    STAGE(Bbase, sB, 0, 0); STAGE(Bbase, sB, 0, 1);
    STAGE(Abase, sA, 1, 0); STAGE(Abase, sA, 1, 1);
    asm volatile("s_waitcnt vmcnt(4)" ::: "memory");   // tile 0 landed; A(1) in flight
    BARRIER();

#pragma unroll 2
    for (int t = 0; t < KT; ++t) {
        const int bo = (t & 1) << 15;
        const int8_t* sAb = sA + bo;
        const int8_t* sBb = sB + bo;
        v4i aF[8][2], bL[2][2], bH[2][2];

        // ---------------- P1: read A[i0..3], B[j0..1]; stage Bh0(t+1); MFMA Q00 ----------------
#pragma unroll
        for (int i = 0; i < 4; ++i) {
            aF[i][0] = *(const v4i*)(sAb + rowA + i * 2048 + xo0);
            aF[i][1] = *(const v4i*)(sAb + rowA + i * 2048 + xo1);
        }
#pragma unroll
        for (int j = 0; j < 2; ++j) {
            bL[j][0] = *(const v4i*)(sBb + rowB + j * 2048 + xo0);
            bL[j][1] = *(const v4i*)(sBb + rowB + j * 2048 + xo1);
        }
        if (t + 1 < KT) STAGE(Bbase, sB, t + 1, 0);
        BARRIER();
        LGKM0();
        PRIO(1);
#pragma unroll
        for (int i = 0; i < 4; ++i)
#pragma unroll
            for (int j = 0; j < 2; ++j) {
                acc[i][j] = MFMA_I8(aF[i][0], bL[j][0], acc[i][j], 0, 0, 0);
                acc[i][j] = MFMA_I8(aF[i][1], bL[j][1], acc[i][j], 0, 0, 0);
            }
        PRIO(0);
        BARRIER();

        // ---------------- P2: read A[i4..7]; stage Bh1(t+1); MFMA Q10 ----------------
#pragma unroll
        for (int i = 4; i < 8; ++i) {
            aF[i][0] = *(const v4i*)(sAb + rowA + i * 2048 + xo0);
            aF[i][1] = *(const v4i*)(sAb + rowA + i * 2048 + xo1);
        }
        if (t + 1 < KT) STAGE(Bbase, sB, t + 1, 1);
        BARRIER();
        LGKM0();
        PRIO(1);
#pragma unroll
        for (int i = 4; i < 8; ++i)
#pragma unroll
            for (int j = 0; j < 2; ++j) {
                acc[i][j] = MFMA_I8(aF[i][0], bL[j][0], acc[i][j], 0, 0, 0);
                acc[i][j] = MFMA_I8(aF[i][1], bL[j][1], acc[i][j], 0, 0, 0);
            }
        PRIO(0);
        BARRIER();

        // ---------------- P3: read B[j2..3]; stage Ah0(t+2); MFMA Q01 ----------------
#pragma unroll
        for (int j = 0; j < 2; ++j) {
            bH[j][0] = *(const v4i*)(sBb + rowB + (j + 2) * 2048 + xo0);
            bH[j][1] = *(const v4i*)(sBb + rowB + (j + 2) * 2048 + xo1);
        }
        if (t + 2 < KT) STAGE(Abase, sA, t + 2, 0);
        BARRIER();
        LGKM0();
        PRIO(1);
#pragma unroll
        for (int i = 0; i < 4; ++i)
#pragma unroll
            for (int j = 0; j < 2; ++j) {
                acc[i][j + 2] = MFMA_I8(aF[i][0], bH[j][0], acc[i][j + 2], 0, 0, 0);
                acc[i][j + 2] = MFMA_I8(aF[i][1], bH[j][1], acc[i][j + 2], 0, 0, 0);
            }
        PRIO(0);
        BARRIER();

        // ---------------- P4: stage Ah1(t+2); vmcnt(4); MFMA Q11 (no reads) ----------------
        if (t + 2 < KT) {
            STAGE(Abase, sA, t + 2, 1);
            asm volatile("s_waitcnt vmcnt(4)" ::: "memory");  // tile t+1 landed; A(t+2) in flight
        } else {
            asm volatile("s_waitcnt vmcnt(0)" ::: "memory");  // tail drain
        }
        BARRIER();
        PRIO(1);
#pragma unroll
        for (int i = 4; i < 8; ++i)
#pragma unroll
            for (int j = 0; j < 2; ++j) {
                acc[i][j + 2] = MFMA_I8(aF[i][0], bH[j][0], acc[i][j + 2], 0, 0, 0);
                acc[i][j + 2] = MFMA_I8(aF[i][1], bH[j][1], acc[i][j + 2], 0, 0, 0);
            }
        PRIO(0);
        BARRIER();
    }
#undef STAGE

    // ---- epilogue. C/D layout (verified): col(n)=lane&15, row(m)=quad*4+reg ----
#pragma unroll
    for (int j = 0; j < 4; ++j) {
        const int n = bn + (wnw << 6) + (j << 4) + tm;
        const float bb = (float)bias[n] * bias_scale;
#pragma unroll
        for (int i = 0; i < 8; ++i) {
            const int mb = bm + (wmw << 7) + (i << 4) + (quad << 2);
#pragma unroll
            for (int r = 0; r < 4; ++r) {
                const float v = (float)acc[i][j][r] * out_scale + bb;
                Y[(size_t)(mb + r) * N + n] = (int)rintf(v);
            }
        }
    }
}

extern "C" void kernel_launch(void* const* d_in, const int* in_sizes, int n_in,
                              void* d_out, int out_size, void* d_ws, size_t ws_size,
                              hipStream_t stream) {
    const int* x32 = (const int*)d_in[0];   // int8 values stored as int32
    const int* w32 = (const int*)d_in[1];
    const int*    bias = (const int*)d_in[2];
    const float*  os   = (const float*)d_in[3];
    const float*  bs   = (const float*)d_in[4];
    int* out = (int*)d_out;

    const int K = KK;
    const int M = in_sizes[0] / K;   // 8192
    const int N = in_sizes[1] / K;   // 4096
    const int nx = in_sizes[0];      // 33554432
    const int nw = in_sizes[1];      // 16777216

    int8_t* x8 = (int8_t*)d_ws;              // 33.5 MB
    int8_t* w8 = x8 + (size_t)nx;            // 16.8 MB  (total 50.3 MB < ws_size)

    pack_i32_to_i8<<<dim3(nx / 4 / 256), dim3(256), 0, stream>>>((const v4i*)x32, (int*)x8, nx / 4);
    pack_i32_to_i8<<<dim3(nw / 4 / 256), dim3(256), 0, stream>>>((const v4i*)w32, (int*)w8, nw / 4);

    dim3 grid((N / BN) * (M / BM));  // 512 blocks = 2 rounds of 256 CUs
    dim3 block(512);
    hipLaunchKernelGGL(w8a8_gemm_kernel, grid, block, 0, stream,
                       x8, w8, bias, os, bs, out, M, N);
}

// Round 3
// 385.326 us; speedup vs baseline: 1.0774x; 1.0774x over previous
//
#include <hip/hip_runtime.h>
#include <stdint.h>

// W8A8B32O32 Linear: Y[m,n] = round(out_scale * sum_k X[m,k]*W[n,k] + bias_scale * bias[n])
// Harness materializes integer inputs as int32 -> pre-pass packs to int8 in d_ws (exact),
// then DMA-staged mfma_i32_16x16x64_i8 GEMM.
//
// Round 8 == Round 7 resubmitted (R7 bench was an infra failure: "container failed twice",
// no counters returned; kernel audited for deadlock -- barriers uniform, vmcnt always
// retirable, 1 block/CU config consistent).
//
// Round 7: fix the Round-6 phase decomposition. R6 put 12/24 per-wave ds_reads in P1
// (96-read CU burst = 1152 cyc serialized against barrier+lgkm0 -> MfmaUtil 34%).
// New phase axis = (A-half, k-slice), B re-read per k-slice: per-wave reads 8/8/4/4,
// max CU burst 64 reads (768 cyc) ~= MFMA cluster (653 cyc). This is the bf16
// template's actual balance (its "4 or 8 reads/phase").
//
//  - 256x256 tile, BK=128, 8 waves (2M x 4N -> 128x64/wave), double-buffered 128 KiB LDS
//  - XOR chunk swizzle (chunk j of row r at slot j^(r&7)) via pre-swizzled global source
//  - phases/tile t (buffer p=t&1):
//      P1: read A[0..3]@k0 + B[0..3]@k0 (8) | stage Ah0(t+1) | 16 MFMA acc[0..3][*]
//      P2: read A[4..7]@k0 + B[0..3]@k1 (8) | stage Ah1(t+1) | 16 MFMA acc[4..7][*]
//      P3: read A[0..3]@k1               (4) | stage Bh0(t+2) | 16 MFMA acc[0..3][*]
//      P4: read A[4..7]@k1               (4) | stage Bh1(t+2) | vmcnt | 16 MFMA acc[4..7][*]
//    each phase: reads+stage -> s_barrier -> lgkmcnt(0) -> setprio(1) MFMA setprio(0) -> s_barrier
//
// Hazard ledger (2 barriers/phase):
//   reads: A(t) last read tP4; B(t) last read tP2  (pre-BAR of those phases)
//   stage Ah(t+1)@tP1/P2 overwrites A(t-1) [retired (t-1)P4, >=2 barriers earlier]  OK
//   stage Bh(t+2)@tP3/P4 overwrites B(t)   [retired tP2,    >=2 barriers earlier]  OK
//   vmcnt(4) at tP4 (after Bh1(t+2) issue): FIFO = [Ah(t+1)x4, Bh(t+2)x4] ->
//     drains A(t+1) + everything older (incl. B(t+1) from (t-1)P3/P4), leaves B(t+2).
//   prologue: A(0)x4, B(0)x4, B(1)x4 -> vmcnt(4) leaves B(1) in flight.
//   tail: vmcnt(0) when t+2 >= KT (drains A(KT-1)).
//
// NOTE: per-replay dur_us includes ~250us fixed harness restore/poison; GEMM is the lever.

typedef int v4i __attribute__((ext_vector_type(4)));

#define BM 256
#define BN 256
#define BK 128
#define KK 4096
#define KT (KK / BK)   // 32

// ---------------- pack: 4x int32 -> 4x int8 in one dword (coalesced, ~roofline) ----------------
__global__ __launch_bounds__(256)
void pack_i32_to_i8(const v4i* __restrict__ src, int* __restrict__ dst, int n4) {
    int i = blockIdx.x * blockDim.x + threadIdx.x;   // one thread = 4 elements
    if (i >= n4) return;
    v4i a = src[i];
    dst[i] = (a[0] & 0xff) | ((a[1] & 0xff) << 8) | ((a[2] & 0xff) << 16) | (a[3] << 24);
}

// ---------------- GEMM ----------------
__device__ __forceinline__ void gld_lds16(const void* g, void* lds) {
    __builtin_amdgcn_global_load_lds(
        (const __attribute__((address_space(1))) unsigned int*)g,
        (__attribute__((address_space(3))) unsigned int*)lds,
        16, 0, 0);
}

#define MFMA_I8 __builtin_amdgcn_mfma_i32_16x16x64_i8
#define BARRIER() __builtin_amdgcn_s_barrier()
#define LGKM0() asm volatile("s_waitcnt lgkmcnt(0)" ::: "memory")
#define PRIO(x) __builtin_amdgcn_s_setprio(x)

__global__ __launch_bounds__(512, 2)
void w8a8_gemm_kernel(const int8_t* __restrict__ X,
                      const int8_t* __restrict__ W,
                      const int*    __restrict__ bias,
                      const float*  __restrict__ out_scale_p,
                      const float*  __restrict__ bias_scale_p,
                      int*          __restrict__ Y,
                      int M, int N)
{
    __shared__ __align__(16) int8_t sA[2 * BM * BK];  // 64 KB (double-buffered)
    __shared__ __align__(16) int8_t sB[2 * BN * BK];  // 64 KB

    const int tid = threadIdx.x;         // 0..511

    // ---- block -> tile mapping with 2D XCD chunking (8 XCDs, each owns 8x8 tiles) ----
    const int nbx = N / BN;              // 16 expected
    const int nby = M / BM;              // 32 expected
    int bx, by;
    {
        const int wg = blockIdx.x;
        if (nbx == 16 && nby == 32) {
            const int x = wg & 7;        // XCD (dispatch round-robins blockIdx % 8)
            const int k = wg >> 3;       // 0..63 within XCD
            bx = ((x & 1) << 3) | (k & 7);
            by = ((x >> 1) << 3) | (k >> 3);
        } else { bx = wg % nbx; by = wg / nbx; }
    }
    const int bn = bx * BN;
    const int bm = by * BM;

    const float out_scale  = *out_scale_p;
    const float bias_scale = *bias_scale_p;

    const int8_t* Abase = X + (size_t)bm * KK;
    const int8_t* Bbase = W + (size_t)bn * KK;

    // ---- staging thread map: half-tile = 128 rows x 8 chunks(16B), 2 gld rounds ----
    // LDS slot c (linear) holds global chunk (c&7)^(row&7) of row c>>3 -> XOR swizzle
    // via SOURCE address permutation; LDS dest stays linear (DMA-compatible).
    const int r0  = tid >> 3;                       // 0..63 (round 0 rows; round 1 = +64)
    const int j0  = tid & 7;
    const int sw  = (j0 ^ (r0 & 7)) << 4;           // pre-swizzled in-row byte offset
    const size_t gOff = (size_t)r0 * KK + sw;
    const int  lOff = tid << 4;

#define STAGE(gbase, lds, t, h) do {                                              \
        const int8_t* _g = (gbase) + (size_t)((h) * 128) * KK                     \
                                   + (size_t)(t) * BK + gOff;                     \
        int8_t* _l = (lds) + (((t) & 1) << 15) + ((h) << 14) + lOff;              \
        gld_lds16(_g,                  _l);                                       \
        gld_lds16(_g + (size_t)64 * KK, _l + 8192);                               \
    } while (0)

    // ---- fragment read map (verified 16x16x64 layout: lane = (tm, quad)) ----
    const int w    = tid >> 6;
    const int l    = tid & 63;
    const int wmw  = w >> 2;                        // 0..1  (M wave)
    const int wnw  = w & 3;                         // 0..3  (N wave)
    const int tm   = l & 15;
    const int quad = l >> 4;
    const int s3   = tm & 7;                        // row&7 (wave row bases are mult of 8)
    const int xo0  = ( quad      ^ s3) << 4;        // kslice 0: chunk quad
    const int xo1  = ((quad + 4) ^ s3) << 4;        // kslice 1: chunk 4+quad
    const int rowA = ((wmw << 7) + tm) << 7;        // (wm*128+tm)*128 bytes
    const int rowB = ((wnw << 6) + tm) << 7;        // (wn*64 +tm)*128 bytes

    v4i acc[8][4];
    const v4i vz = {0, 0, 0, 0};
#pragma unroll
    for (int i = 0; i < 8; ++i)
#pragma unroll
        for (int j = 0; j < 4; ++j)
            acc[i][j] = vz;

    // ---- prologue: A(0), B(0), B(1); A(1) comes in-loop at t=0 P1/P2 ----
    STAGE(Abase, sA, 0, 0); STAGE(Abase, sA, 0, 1);
    STAGE(Bbase, sB, 0, 0); STAGE(Bbase, sB, 0, 1);
    STAGE(Bbase, sB, 1, 0); STAGE(Bbase, sB, 1, 1);
    asm volatile("s_waitcnt vmcnt(4)" ::: "memory");   // A(0),B(0) landed; B(1) in flight
    BARRIER();

#pragma unroll 2
    for (int t = 0; t < KT; ++t) {
        const int bo = (t & 1) << 15;
        const int8_t* sAb = sA + bo;
        const int8_t* sBb = sB + bo;
        v4i a0[4], a1[4], b0[4], b1[4];

        // ---------------- P1: read A[0..3]@k0 + B@k0; stage Ah0(t+1); MFMA top@k0 ----------------
#pragma unroll
        for (int i = 0; i < 4; ++i)
            a0[i] = *(const v4i*)(sAb + rowA + i * 2048 + xo0);
#pragma unroll
        for (int j = 0; j < 4; ++j)
            b0[j] = *(const v4i*)(sBb + rowB + j * 2048 + xo0);
        if (t + 1 < KT) STAGE(Abase, sA, t + 1, 0);
        BARRIER();
        LGKM0();
        PRIO(1);
#pragma unroll
        for (int i = 0; i < 4; ++i)
#pragma unroll
            for (int j = 0; j < 4; ++j)
                acc[i][j] = MFMA_I8(a0[i], b0[j], acc[i][j], 0, 0, 0);
        PRIO(0);
        BARRIER();

        // ---------------- P2: read A[4..7]@k0 + B@k1; stage Ah1(t+1); MFMA bot@k0 ----------------
#pragma unroll
        for (int i = 0; i < 4; ++i)
            a1[i] = *(const v4i*)(sAb + rowA + (i + 4) * 2048 + xo0);
#pragma unroll
        for (int j = 0; j < 4; ++j)
            b1[j] = *(const v4i*)(sBb + rowB + j * 2048 + xo1);
        if (t + 1 < KT) STAGE(Abase, sA, t + 1, 1);
        BARRIER();
        LGKM0();
        PRIO(1);
#pragma unroll
        for (int i = 0; i < 4; ++i)
#pragma unroll
            for (int j = 0; j < 4; ++j)
                acc[i + 4][j] = MFMA_I8(a1[i], b0[j], acc[i + 4][j], 0, 0, 0);
        PRIO(0);
        BARRIER();

        // ---------------- P3: read A[0..3]@k1; stage Bh0(t+2); MFMA top@k1 ----------------
#pragma unroll
        for (int i = 0; i < 4; ++i)
            a0[i] = *(const v4i*)(sAb + rowA + i * 2048 + xo1);
        if (t + 2 < KT) STAGE(Bbase, sB, t + 2, 0);
        BARRIER();
        LGKM0();
        PRIO(1);
#pragma unroll
        for (int i = 0; i < 4; ++i)
#pragma unroll
            for (int j = 0; j < 4; ++j)
                acc[i][j] = MFMA_I8(a0[i], b1[j], acc[i][j], 0, 0, 0);
        PRIO(0);
        BARRIER();

        // ---------------- P4: read A[4..7]@k1; stage Bh1(t+2); vmcnt; MFMA bot@k1 ----------------
#pragma unroll
        for (int i = 0; i < 4; ++i)
            a1[i] = *(const v4i*)(sAb + rowA + (i + 4) * 2048 + xo1);
        if (t + 2 < KT) {
            STAGE(Bbase, sB, t + 2, 1);
            asm volatile("s_waitcnt vmcnt(4)" ::: "memory");  // A(t+1)+older landed; B(t+2) in flight
        } else {
            asm volatile("s_waitcnt vmcnt(0)" ::: "memory");  // tail drain (A(KT-1))
        }
        BARRIER();
        LGKM0();
        PRIO(1);
#pragma unroll
        for (int i = 0; i < 4; ++i)
#pragma unroll
            for (int j = 0; j < 4; ++j)
                acc[i + 4][j] = MFMA_I8(a1[i], b1[j], acc[i + 4][j], 0, 0, 0);
        PRIO(0);
        BARRIER();
    }
#undef STAGE

    // ---- epilogue. C/D layout (verified): col(n)=lane&15, row(m)=quad*4+reg ----
    // j-inner store order: both 64B halves of each 128B L2 line written back-to-back.
    float bb[4];
#pragma unroll
    for (int j = 0; j < 4; ++j)
        bb[j] = (float)bias[bn + (wnw << 6) + (j << 4) + tm] * bias_scale;
#pragma unroll
    for (int i = 0; i < 8; ++i) {
        const int mb = bm + (wmw << 7) + (i << 4) + (quad << 2);
#pragma unroll
        for (int r = 0; r < 4; ++r) {
            int* yrow = Y + (size_t)(mb + r) * N + bn + (wnw << 6) + tm;
#pragma unroll
            for (int j = 0; j < 4; ++j) {
                const float v = (float)acc[i][j][r] * out_scale + bb[j];
                yrow[j << 4] = (int)rintf(v);
            }
        }
    }
}

extern "C" void kernel_launch(void* const* d_in, const int* in_sizes, int n_in,
                              void* d_out, int out_size, void* d_ws, size_t ws_size,
                              hipStream_t stream) {
    const int* x32 = (const int*)d_in[0];   // int8 values stored as int32
    const int* w32 = (const int*)d_in[1];
    const int*    bias = (const int*)d_in[2];
    const float*  os   = (const float*)d_in[3];
    const float*  bs   = (const float*)d_in[4];
    int* out = (int*)d_out;

    const int K = KK;
    const int M = in_sizes[0] / K;   // 8192
    const int N = in_sizes[1] / K;   // 4096
    const int nx = in_sizes[0];      // 33554432
    const int nw = in_sizes[1];      // 16777216

    int8_t* x8 = (int8_t*)d_ws;              // 33.5 MB
    int8_t* w8 = x8 + (size_t)nx;            // 16.8 MB  (total 50.3 MB < ws_size)

    pack_i32_to_i8<<<dim3(nx / 4 / 256), dim3(256), 0, stream>>>((const v4i*)x32, (int*)x8, nx / 4);
    pack_i32_to_i8<<<dim3(nw / 4 / 256), dim3(256), 0, stream>>>((const v4i*)w32, (int*)w8, nw / 4);

    dim3 grid((N / BN) * (M / BM));  // 512 blocks = 2 rounds of 256 CUs
    dim3 block(512);
    hipLaunchKernelGGL(w8a8_gemm_kernel, grid, block, 0, stream,
                       x8, w8, bias, os, bs, out, M, N);
}